// Round 2
// baseline (17.875 us; speedup 1.0000x reference)
//
#include <hip/hip_runtime.h>

#define B_ 2048
#define S_ 512
#define V_ 32128
#define H_ 16
#define O_ 16

__device__ __forceinline__ unsigned bf16rne(float f) {
    unsigned x = __float_as_uint(f);
    return (x + 0x7fffu + ((x >> 16) & 1u)) >> 16;
}

// ---------------------------------------------------------------------------
// Transpose + downconvert enc1_w [16, V] f32 -> wT [V, 16] bf16 (32 B/token).
// V = 32128 = 251 * 128. Coalesced reads and coalesced packed-u32 writes.
// ---------------------------------------------------------------------------
__global__ __launch_bounds__(256) void transpose_w_bf16_kernel(
    const float* __restrict__ w,      // [16, V]
    unsigned* __restrict__ wT)        // [V, 8] packed bf16 pairs (h=2k,2k+1)
{
    __shared__ float tile[16][129];
    const int t  = threadIdx.x;
    const int v0 = blockIdx.x * 128;

#pragma unroll
    for (int i = 0; i < 8; ++i) {          // 16 rows x 128 cols
        int idx = i * 256 + t;
        int h   = idx >> 7;
        int vl  = idx & 127;
        tile[h][vl] = w[(size_t)h * V_ + v0 + vl];
    }
    __syncthreads();
#pragma unroll
    for (int i = 0; i < 4; ++i) {          // 1024 packed u32 / 256 threads
        int u  = i * 256 + t;
        int vl = u >> 3;                   // 0..127
        int hw = u & 7;                    // h-pair index
        unsigned lo = bf16rne(tile[2 * hw][vl]);
        unsigned hi = bf16rne(tile[2 * hw + 1][vl]);
        wT[(size_t)(v0 + vl) * 8 + hw] = lo | (hi << 16);
    }
}

// ---------------------------------------------------------------------------
// One WAVE per batch row (4 rows / 256-thread block, grid B/4). No block-wide
// barriers: staging, gather-accumulate, butterfly reduce, and the 16x16
// matvecs are all within-wave. 32 groups x 2 lanes; group g handles tokens
// j*32+g (LDS bank = g: conflict-free broadcast); lane half p owns h[8p:8p+8).
// ---------------------------------------------------------------------------
__global__ __launch_bounds__(256) void encoder_bf16_kernel(
    const int*   __restrict__ x,        // [B, S]
    const uint4* __restrict__ wT,       // [V][2] uint4 = [V][16] bf16
    const float* __restrict__ enc1_b,   // [16]
    const float* __restrict__ mean_w,   // [16,16]
    const float* __restrict__ mean_b,   // [16]
    const float* __restrict__ logvar_w, // [16,16]
    const float* __restrict__ logvar_b, // [16]
    float*       __restrict__ out)      // mean [B,16] then logvar [B,16]
{
    __shared__ int   toks[4][S_];
    __shared__ float hvec[4][16];

    const int t    = threadIdx.x;
    const int wave = t >> 6;
    const int lane = t & 63;
    const int b    = blockIdx.x * 4 + wave;

    // Stage this wave's 512 token ids (2x int4 per lane, coalesced).
    {
        const int4* xr = (const int4*)(x + (size_t)b * S_);
        int4 t0 = xr[lane * 2];
        int4 t1 = xr[lane * 2 + 1];
        ((int4*)toks[wave])[lane * 2]     = t0;
        ((int4*)toks[wave])[lane * 2 + 1] = t1;
    }
    // Same-wave LDS RAW: compiler inserts lgkmcnt wait; no barrier needed.

    const int g = lane >> 1;   // token group 0..31
    const int p = lane & 1;    // h-half: h[8p .. 8p+8)

    float a[8];
#pragma unroll
    for (int k = 0; k < 8; ++k) a[k] = 0.0f;

#pragma unroll
    for (int j = 0; j < 16; ++j) {
        int v = toks[wave][j * 32 + g];
        uint4 wv = wT[(size_t)v * 2 + p];
        a[0] += __uint_as_float(wv.x << 16);
        a[1] += __uint_as_float(wv.x & 0xffff0000u);
        a[2] += __uint_as_float(wv.y << 16);
        a[3] += __uint_as_float(wv.y & 0xffff0000u);
        a[4] += __uint_as_float(wv.z << 16);
        a[5] += __uint_as_float(wv.z & 0xffff0000u);
        a[6] += __uint_as_float(wv.w << 16);
        a[7] += __uint_as_float(wv.w & 0xffff0000u);
    }

    // Butterfly across the 32 groups (bit 0 = p preserved).
#pragma unroll
    for (int m = 2; m <= 32; m <<= 1) {
#pragma unroll
        for (int k = 0; k < 8; ++k) a[k] += __shfl_xor(a[k], m);
    }

    if (lane < 2) {            // lane == p
#pragma unroll
        for (int k = 0; k < 8; ++k) {
            float s = a[k] + enc1_b[p * 8 + k];
            hvec[wave][p * 8 + k] = fmaxf(s, 0.0f);
        }
    }

    // Two 16x16 matvecs: lanes 0..15 -> mean, lanes 16..31 -> logvar.
    if (lane < 32) {
        const int    o   = lane & 15;
        const int    sel = lane >> 4;
        const float* W   = sel ? logvar_w : mean_w;
        const float* Bv  = sel ? logvar_b : mean_b;
        float s = Bv[o];
#pragma unroll
        for (int k = 0; k < 16; ++k) s += W[o * 16 + k] * hvec[wave][k];
        out[(size_t)sel * B_ * O_ + (size_t)b * O_ + o] = s;
    }
}

// ---------------------------------------------------------------------------
// Fallback (no workspace): gather straight from enc1_w [16, V] f32.
// ---------------------------------------------------------------------------
__global__ __launch_bounds__(256) void encoder_f32_fallback_kernel(
    const int*   __restrict__ x,
    const float* __restrict__ table,    // [16, V]
    const float* __restrict__ enc1_b,
    const float* __restrict__ mean_w,
    const float* __restrict__ mean_b,
    const float* __restrict__ logvar_w,
    const float* __restrict__ logvar_b,
    float*       __restrict__ out)
{
    __shared__ int   toks[S_];
    __shared__ float hred[4][16];
    __shared__ float hvec[16];

    const int t = threadIdx.x;
    const int b = blockIdx.x;
    {
        const int2* xr = (const int2*)(x + (size_t)b * S_);
        ((int2*)toks)[t] = xr[t];
    }
    __syncthreads();

    const int q = t & 3;
    const int g = t >> 2;
    float a0 = 0.f, a1 = 0.f, a2 = 0.f, a3 = 0.f;
#pragma unroll
    for (int j = 0; j < 8; ++j) {
        int v = toks[j * 64 + g];
        a0 += table[(size_t)(q * 4 + 0) * V_ + v];
        a1 += table[(size_t)(q * 4 + 1) * V_ + v];
        a2 += table[(size_t)(q * 4 + 2) * V_ + v];
        a3 += table[(size_t)(q * 4 + 3) * V_ + v];
    }
#pragma unroll
    for (int m = 4; m <= 32; m <<= 1) {
        a0 += __shfl_xor(a0, m);
        a1 += __shfl_xor(a1, m);
        a2 += __shfl_xor(a2, m);
        a3 += __shfl_xor(a3, m);
    }
    const int wave = t >> 6;
    const int lane = t & 63;
    if (lane < 4) {
        hred[wave][lane * 4 + 0] = a0;
        hred[wave][lane * 4 + 1] = a1;
        hred[wave][lane * 4 + 2] = a2;
        hred[wave][lane * 4 + 3] = a3;
    }
    __syncthreads();
    if (t < 16) {
        float s = hred[0][t] + hred[1][t] + hred[2][t] + hred[3][t] + enc1_b[t];
        hvec[t] = fmaxf(s, 0.0f);
    }
    __syncthreads();
    if (t < 32) {
        const int    o  = t & 15;
        const float* W  = (t < 16) ? mean_w : logvar_w;
        const float* Bv = (t < 16) ? mean_b : logvar_b;
        float s = Bv[o];
#pragma unroll
        for (int k = 0; k < 16; ++k) s += W[o * 16 + k] * hvec[k];
        const size_t off = (t < 16) ? 0 : (size_t)B_ * O_;
        out[off + (size_t)b * O_ + o] = s;
    }
}

extern "C" void kernel_launch(void* const* d_in, const int* in_sizes, int n_in,
                              void* d_out, int out_size, void* d_ws, size_t ws_size,
                              hipStream_t stream) {
    const int*   x        = (const int*)d_in[0];
    const float* enc1_w   = (const float*)d_in[1];
    const float* enc1_b   = (const float*)d_in[2];
    const float* mean_w   = (const float*)d_in[3];
    const float* mean_b   = (const float*)d_in[4];
    const float* logvar_w = (const float*)d_in[5];
    const float* logvar_b = (const float*)d_in[6];
    float*       out      = (float*)d_out;

    const size_t wT_bytes = (size_t)V_ * H_ * 2;   // bf16 table
    if (ws_size >= wT_bytes) {
        unsigned* wT = (unsigned*)d_ws;
        transpose_w_bf16_kernel<<<V_ / 128, 256, 0, stream>>>(enc1_w, wT);
        encoder_bf16_kernel<<<B_ / 4, 256, 0, stream>>>(
            x, (const uint4*)wT, enc1_b, mean_w, mean_b, logvar_w, logvar_b, out);
    } else {
        encoder_f32_fallback_kernel<<<B_, 256, 0, stream>>>(
            x, enc1_w, enc1_b, mean_w, mean_b, logvar_w, logvar_b, out);
    }
}